// Round 4
// baseline (58.620 us; speedup 1.0000x reference)
//
#include <hip/hip_runtime.h>
#include <math.h>

constexpr int H_ = 180, W_ = 320, RF_ = 16, K_ = 20, T_ = 400;
constexpr int HW_ = H_ * W_;
constexpr int NWIN = T_ - K_ + 1;   // 381
constexpr int PW   = W_ + 2 * RF_;  // 352 (padded width used by rf_indices)
constexpr float ALPHA = 50.0f, BETA = 1.0f, GAMMA = 0.0f;
constexpr int NXCD = 8;
constexpr int T_PER_XCD = T_ / NXCD;   // 50 frames per XCD
constexpr int CH = 8;                  // frames per reduction chunk

__device__ inline float wave_sum(float v) {
#pragma unroll
    for (int off = 1; off < 64; off <<= 1)
        v += __shfl_xor(v, off, 64);
    return v;
}

// ---------------------------------------------------------------------------
// Kernel 0: factorize w (K x 256) into temporal[K] (x) spatial[256].
// w is an exact rank-1 outer product; LS-project onto the largest row.
// ---------------------------------------------------------------------------
__global__ void factorize_kernel(const float* __restrict__ w,
                                 float* __restrict__ spatial,   // 256
                                 float* __restrict__ temporal)  // K
{
    int l = threadIdx.x;  // 0..63
    float best = -1.0f;
    int k0 = 0;
    for (int k = 0; k < K_; ++k) {
        float s = 0.0f;
#pragma unroll
        for (int j = 0; j < 4; ++j) {
            float v = w[k * 256 + l + j * 64];
            s = fmaf(v, v, s);
        }
        s = wave_sum(s);
        if (s > best) { best = s; k0 = k; }
    }
#pragma unroll
    for (int j = 0; j < 4; ++j)
        spatial[l + j * 64] = w[k0 * 256 + l + j * 64];
    float inv_s2 = 1.0f / best;
    for (int k = 0; k < K_; ++k) {
        float d = 0.0f;
#pragma unroll
        for (int j = 0; j < 4; ++j)
            d = fmaf(w[k * 256 + l + j * 64], w[k0 * 256 + l + j * 64], d);
        d = wave_sum(d);
        if (l == 0) temporal[k] = d * inv_s2;
    }
}

// ---------------------------------------------------------------------------
// Kernel 1: y[n, t] = sum_p x_patch[t, n, p] * spatial[p]
//
// One wave per (neuron, 50-frame XCD range). Lane l loads ONE float4 per
// frame: row r0c+(l>>2), cols c0c+4*(l&3) -> whole 256-px RF in a single
// wave instruction. The 16x16 window origin is CLAMPED into the frame (all
// loads in-bounds); zero-pad semantics recovered by shifting/zeroing the
// per-lane weights (computed once per wave).
//
// 8 frames per chunk: 8 independent load->FMA chains, then a multi-value
// butterfly (4+2+1 halving exchanges + 3 full steps = 10 shuffles for 8
// wave-sums). Lane bitrev3(l&7) holds frame tt+f -> coalesced 8-lane store.
// ---------------------------------------------------------------------------
__global__ __launch_bounds__(256) void stage1_kernel(
    const float* __restrict__ x, const int* __restrict__ rf,
    const float* __restrict__ spatial, float* __restrict__ y,
    int N)
{
    int lane = threadIdx.x & 63;
    int wid  = threadIdx.x >> 6;

    int b   = blockIdx.x;
    int xcd = b & (NXCD - 1);
    int nch = b >> 3;

    int n = nch * 4 + wid;
    if (n >= N) return;
    int t0 = xcd * T_PER_XCD;

    int base = rf[n * 256];          // = v*PW + h (first padded index)
    int r0 = base / PW - RF_;        // window origin in frame (may be <0)
    int c0 = base % PW - RF_;
    int r0c = min(max(r0, 0), H_ - RF_);   // clamped origin (loads in-bounds)
    int c0c = min(max(c0, 0), W_ - RF_);

    int lr = lane >> 2;              // window row 0..15
    int q  = lane & 3;               // column quad 0..3
    int off = (r0c + lr) * W_ + c0c + q * 4;

    // weights matched to the CLAMPED window; outside true RF -> 0 (zero-pad)
    float wv[4];
    int rr = lr + (r0c - r0);
#pragma unroll
    for (int j = 0; j < 4; ++j) {
        int cc = q * 4 + j + (c0c - c0);
        bool ok = (rr >= 0) & (rr < RF_) & (cc >= 0) & (cc < RF_);
        wv[j] = ok ? spatial[rr * RF_ + cc] : 0.0f;
    }

    const float* xp = x + (size_t)t0 * HW_;
    float* yp = y + (size_t)n * T_ + t0;

    int fr_out = ((lane & 1) << 2) | (lane & 2) | ((lane & 4) >> 2); // bitrev3

    for (int tt = 0; tt < T_PER_XCD; tt += CH) {
        float acc[CH];
#pragma unroll
        for (int j = 0; j < CH; ++j) {
            int f = tt + j;
            f = f < T_PER_XCD ? f : T_PER_XCD - 1;   // scalar clamp (tail)
            float4 v = *reinterpret_cast<const float4*>(xp + (size_t)f * HW_ + off);
            float a = v.x * wv[0];
            a = fmaf(v.y, wv[1], a);
            a = fmaf(v.z, wv[2], a);
            acc[j] = fmaf(v.w, wv[3], a);
        }
        // halving-exchange multi-reduce: 8 wave-sums in 10 shuffles
#pragma unroll
        for (int s = 0; s < 3; ++s) {
            const int m = 1 << s;
            const int half = CH >> (s + 1);   // 4,2,1
            bool hi = (lane & m) != 0;
            float nv[CH / 2];
#pragma unroll
            for (int j = 0; j < half; ++j) {
                float keep = hi ? acc[half + j] : acc[j];
                float send = hi ? acc[j] : acc[half + j];
                nv[j] = keep + __shfl_xor(send, m, 64);
            }
#pragma unroll
            for (int j = 0; j < half; ++j) acc[j] = nv[j];
        }
        float r = acc[0];
        r += __shfl_xor(r, 8, 64);
        r += __shfl_xor(r, 16, 64);
        r += __shfl_xor(r, 32, 64);
        if (lane < 8 && tt + fr_out < T_PER_XCD)
            yp[tt + fr_out] = r;
    }
}

// ---------------------------------------------------------------------------
// Kernel 2: out[n, t0] = ALPHA * softplus(BETA * (sum_k y[n,t0+k]*temporal[k]
//                                                  - GAMMA))
// ---------------------------------------------------------------------------
__global__ void stage2_kernel(const float* __restrict__ y,
                              const float* __restrict__ temporal,
                              float* __restrict__ out, int N)
{
    __shared__ float tw[K_];
    if (threadIdx.x < K_) tw[threadIdx.x] = temporal[threadIdx.x];
    __syncthreads();

    int n  = blockIdx.x;
    int t0 = threadIdx.x;
    if (n >= N || t0 >= NWIN) return;

    const float* yn = y + (size_t)n * T_;
    float g = 0.0f;
#pragma unroll
    for (int k = 0; k < K_; ++k)
        g = fmaf(yn[t0 + k], tw[k], g);

    float z = BETA * (g - GAMMA);
    float sp = fmaxf(z, 0.0f) + log1pf(expf(-fabsf(z)));
    out[n * NWIN + t0] = ALPHA * sp;
}

// ---------------------------------------------------------------------------
extern "C" void kernel_launch(void* const* d_in, const int* in_sizes, int n_in,
                              void* d_out, int out_size, void* d_ws, size_t ws_size,
                              hipStream_t stream)
{
    const float* x  = (const float*)d_in[0];  // (T, H, W) f32
    const float* w  = (const float*)d_in[1];  // (K*RF*RF,) f32
    const int*   rf = (const int*)d_in[2];    // (N, 256) i32

    int N   = in_sizes[2] / (RF_ * RF_);
    int NCH = (N + 3) / 4;                    // 4 neurons (waves) per block

    float* spatial  = (float*)d_ws;           // 256
    float* temporal = spatial + 256;          // 20 (pad to 512)
    float* y        = spatial + 512;          // N * T

    factorize_kernel<<<1, 64, 0, stream>>>(w, spatial, temporal);
    stage1_kernel<<<NXCD * NCH, 256, 0, stream>>>(x, rf, spatial, y, N);
    stage2_kernel<<<N, 384, 0, stream>>>(y, temporal, (float*)d_out, N);
}